// Round 9
// baseline (152.252 us; speedup 1.0000x reference)
//
#include <hip/hip_runtime.h>

#define NCLS 1024
#define DIM  256
#define NTOT 2048   // 2*NCLS rows in "total"
#define GBATCH 16   // rows per wave pipeline batch (16 KB in flight per wave)

typedef float f32x4 __attribute__((ext_vector_type(4)));

__device__ __forceinline__ float4 f4add(float4 a, float4 b){
  return make_float4(a.x+b.x, a.y+b.y, a.z+b.z, a.w+b.w);
}

// ---------------- init ---------------------------------------------------------
__global__ void k_init(int* counts, double* lossacc){
  int t = threadIdx.x;
  if (t < NCLS) counts[t] = 0;
  if (t == 0) *lossacc = 0.0;
}

// ---------------- histogram of targets (LDS-staged) ---------------------------
__global__ __launch_bounds__(256) void k_hist(const int* __restrict__ tgt, int n,
                                              int* __restrict__ counts){
  __shared__ int h[NCLS];
  for (int i = threadIdx.x; i < NCLS; i += blockDim.x) h[i] = 0;
  __syncthreads();
  for (int i = blockIdx.x*blockDim.x + threadIdx.x; i < n; i += gridDim.x*blockDim.x)
    atomicAdd(&h[tgt[i]], 1);
  __syncthreads();
  for (int i = threadIdx.x; i < NCLS; i += blockDim.x)
    if (h[i]) atomicAdd(&counts[i], h[i]);
}

// ---------------- exclusive scan over 1024 counts (single block) --------------
__global__ void k_scan(const int* __restrict__ counts, int* __restrict__ offsets,
                       int* __restrict__ cursor){
  __shared__ int buf[NCLS];
  int t = threadIdx.x;
  int v = counts[t];
  buf[t] = v;
  __syncthreads();
  for (int o = 1; o < NCLS; o <<= 1){
    int u = (t >= o) ? buf[t-o] : 0;
    __syncthreads();
    buf[t] += u;
    __syncthreads();
  }
  int excl = buf[t] - v;
  offsets[t] = excl;
  cursor[t]  = excl;
}

// ---------------- counting-sort scatter: per-class row lists ------------------
__global__ __launch_bounds__(256) void k_scatter(const int* __restrict__ tgt, int n,
                                                 int* __restrict__ cursor,
                                                 int* __restrict__ index){
  for (int i = blockIdx.x*blockDim.x + threadIdx.x; i < n; i += gridDim.x*blockDim.x){
    int t = tgt[i];
    int pos = atomicAdd(&cursor[t], 1);
    index[pos] = i;
  }
}

// ---------------- partial gather: global_load_lds deep pipeline ----------------
// bid = cls*4 + h*2 + a. Each wave issues GBATCH fire-and-forget row loads
// (global_load_lds, no VGPR dest) into a private 16KB LDS region, drains vmcnt
// once, then reduces from LDS. 128 KB outstanding per CU — decisive test of
// CU-issue-limit (a) vs fabric random-pattern ceiling (b).
__global__ __launch_bounds__(256) void k_gather(const float* __restrict__ xr,
    const float* __restrict__ xi, const int* __restrict__ index,
    const int* __restrict__ counts, const int* __restrict__ offsets,
    float* __restrict__ Ppart)
{
  __shared__ int idx_sh[256];
  __shared__ float buf[4*GBATCH*256];    // 4 waves * 16 rows * 1KB = 64 KB
  int bid = blockIdx.x;
  int cls = bid >> 2;
  int h   = (bid >> 1) & 1;
  int a   = bid & 1;
  int tid = threadIdx.x;
  int l = tid & 63, g = tid >> 6;
  int cnt = counts[cls], off = offsets[cls];
  int c0 = (cnt + 1) >> 1;
  int start = off + (h ? c0 : 0);
  int total = (h ? (cnt - c0) : c0);
  const float* __restrict__ X = a ? xi : xr;

  for (int i = tid; i < total; i += 256) idx_sh[i] = index[start + i];
  __syncthreads();

  float* wbuf = buf + g*(GBATCH*256);    // wave-private 16 KB
  f32x4 acc = {0.f, 0.f, 0.f, 0.f};
  int nw = (total > g) ? ((total - g + 3) >> 2) : 0;   // rows for wave g (p = g+4i)

  int i = 0;
  while (i < nw){
    int m = nw - i; if (m > GBATCH) m = GBATCH;
    for (int k = 0; k < m; ++k){
      unsigned row = (unsigned)idx_sh[g + 4*(i + k)];
      const float* gsrc = X + (size_t)row*DIM + (unsigned)l*4;  // lane's 16B
      __builtin_amdgcn_global_load_lds(gsrc, wbuf + k*256, 16, 0, 0);
    }
    asm volatile("s_waitcnt vmcnt(0)" ::: "memory");
    __builtin_amdgcn_sched_barrier(0);
    for (int k = 0; k < m; ++k){
      f32x4 v = *(const f32x4*)(wbuf + k*256 + l*4);
      acc += v;
    }
    i += m;
  }

  __syncthreads();                        // all waves done with buf
  f32x4* sh4 = (f32x4*)buf;
  sh4[tid] = acc;
  __syncthreads();
  if (tid < 64){
    f32x4 r = (sh4[tid] + sh4[tid+64]) + (sh4[tid+128] + sh4[tid+192]);
    float4 o; o.x = r.x; o.y = r.y; o.z = r.z; o.w = r.w;
    ((float4*)Ppart)[bid*64 + tid] = o;
  }
}

// ---------------- combine partials -> T rows + sq (NO atomics) -----------------
// One wave per (cls, a): 512 blocks x 256 threads.
__global__ __launch_bounds__(256) void k_combine(const float* __restrict__ Ppart,
    const int* __restrict__ counts, float* __restrict__ T, float* __restrict__ sq)
{
  int wv  = blockIdx.x*4 + (threadIdx.x >> 6);   // 0..2047 = cls*2 + a
  int cls = wv >> 1, a = wv & 1;
  int l   = threadIdx.x & 63;
  const float4* P4 = (const float4*)Ppart;
  float4 p0 = P4[(cls*4 + 0 + a)*64 + l];
  float4 p1 = P4[(cls*4 + 2 + a)*64 + l];
  float invd = 1.f / fmaxf((float)counts[cls], 1.f);
  float4 c;
  c.x = (p0.x + p1.x) * invd;
  c.y = (p0.y + p1.y) * invd;
  c.z = (p0.z + p1.z) * invd;
  c.w = (p0.w + p1.w) * invd;
  int row = a ? (NCLS + cls) : cls;
  ((float4*)T)[row*64 + l] = c;
  float v = c.x*c.x + c.y*c.y + c.z*c.z + c.w*c.w;
  #pragma unroll
  for (int o = 32; o > 0; o >>= 1) v += __shfl_down(v, o);
  if (l == 0) sq[row] = v;
}

// ---------------- column-sum partials of T (NO atomics) ------------------------
__global__ __launch_bounds__(256) void k_colsum(const float* __restrict__ T,
                                                float* __restrict__ Pcol){
  int b = blockIdx.x;
  int tid = threadIdx.x;
  int l = tid & 63, g = tid >> 6;
  const float4* T4 = (const float4*)T;
  float4 acc = make_float4(0,0,0,0);
  for (int r = b*64 + g; r < b*64 + 64; r += 4)
    acc = f4add(acc, T4[r*64 + l]);
  __shared__ float4 sh[256];
  sh[tid] = acc; __syncthreads();
  if (tid < 64){
    float4 r = f4add(f4add(sh[tid], sh[tid+64]), f4add(sh[tid+128], sh[tid+192]));
    ((float4*)Pcol)[b*64 + tid] = r;
  }
}

// ---------------- bandwidth: reduce sq + ||colsum||^2 --------------------------
// sum(dists) = 2n*sum(sq) - 2*||colsum||^2  (clamp affects only ~1e-6 diag noise)
__global__ __launch_bounds__(256) void k_bw(const float* __restrict__ sq,
    const float* __restrict__ Pcol, float* __restrict__ invbw){
  int t = threadIdx.x;
  double acc = 0.0;
  for (int i = t; i < NTOT; i += 256) acc += (double)sq[i];
  float cs = 0.f;
  for (int b = 0; b < 32; ++b) cs += Pcol[b*DIM + t];
  double c2 = (double)cs * (double)cs;
  #pragma unroll
  for (int o = 32; o > 0; o >>= 1){
    acc += __shfl_down(acc, o);
    c2  += __shfl_down(c2, o);
  }
  __shared__ double ra[4], rc[4];
  int lane = t & 63, wid = t >> 6;
  if (lane == 0){ ra[wid] = acc; rc[wid] = c2; }
  __syncthreads();
  if (t == 0){
    double S_sq = ra[0]+ra[1]+ra[2]+ra[3];
    double S_cs = rc[0]+rc[1]+rc[2]+rc[3];
    double S1 = 2.0*(double)NTOT*S_sq - 2.0*S_cs;
    double bw = S1 / ((double)NTOT*(double)NTOT - (double)NTOT) / 4.0;
    #pragma unroll
    for (int k = 0; k < 5; ++k)
      invbw[k] = (float)(1.0 / (bw * (double)(1 << k)));
  }
}

// ---------------- fused Gram + 5-exp kernel + signed reduction ----------------
__global__ __launch_bounds__(256) void k_mmd(const float* __restrict__ T,
    const float* __restrict__ sq, const float* __restrict__ invbw,
    double* __restrict__ lossacc)
{
  __shared__ float As[64][68];
  __shared__ float Bs[64][68];
  __shared__ float red[4];
  int bx = blockIdx.x, by = blockIdx.y;
  int tid = threadIdx.x;
  int tx = tid & 15, ty = tid >> 4;
  int rowA = by*64, rowB = bx*64;
  float acc[4][4];
  #pragma unroll
  for (int a = 0; a < 4; ++a)
    #pragma unroll
    for (int b = 0; b < 4; ++b) acc[a][b] = 0.f;

  for (int kk = 0; kk < DIM; kk += 64){
    #pragma unroll
    for (int it = 0; it < 4; ++it){
      int idx = it*256 + tid;
      int r = idx >> 4, c4 = idx & 15;
      float4 va = *(const float4*)&T[(rowA + r)*DIM + kk + c4*4];
      float4 vb = *(const float4*)&T[(rowB + r)*DIM + kk + c4*4];
      *(float4*)&As[r][c4*4] = va;
      *(float4*)&Bs[r][c4*4] = vb;
    }
    __syncthreads();
    #pragma unroll 8
    for (int k = 0; k < 64; ++k){
      float a0 = As[ty*4+0][k], a1 = As[ty*4+1][k], a2 = As[ty*4+2][k], a3 = As[ty*4+3][k];
      float b0 = Bs[tx*4+0][k], b1 = Bs[tx*4+1][k], b2 = Bs[tx*4+2][k], b3 = Bs[tx*4+3][k];
      acc[0][0] += a0*b0; acc[0][1] += a0*b1; acc[0][2] += a0*b2; acc[0][3] += a0*b3;
      acc[1][0] += a1*b0; acc[1][1] += a1*b1; acc[1][2] += a1*b2; acc[1][3] += a1*b3;
      acc[2][0] += a2*b0; acc[2][1] += a2*b1; acc[2][2] += a2*b2; acc[2][3] += a2*b3;
      acc[3][0] += a3*b0; acc[3][1] += a3*b1; acc[3][2] += a3*b2; acc[3][3] += a3*b3;
    }
    __syncthreads();
  }

  float i0 = invbw[0], i1 = invbw[1], i2 = invbw[2], i3 = invbw[3], i4 = invbw[4];
  float lacc = 0.f;
  #pragma unroll
  for (int a = 0; a < 4; ++a){
    int i = rowA + ty*4 + a;
    float sqi  = sq[i];
    float sgnI = (i < NCLS) ? 1.f : -1.f;
    #pragma unroll
    for (int b = 0; b < 4; ++b){
      int j = rowB + tx*4 + b;
      float d = sqi + sq[j] - 2.f*acc[a][b];
      d = fmaxf(d, 0.f);
      float w = __expf(-d*i0) + __expf(-d*i1) + __expf(-d*i2) + __expf(-d*i3) + __expf(-d*i4);
      lacc += ((j < NCLS) ? sgnI : -sgnI) * w;
    }
  }
  #pragma unroll
  for (int o = 32; o > 0; o >>= 1) lacc += __shfl_down(lacc, o);
  int lane = tid & 63, wid = tid >> 6;
  if (lane == 0) red[wid] = lacc;
  __syncthreads();
  if (tid == 0) atomicAdd(lossacc, (double)(red[0]+red[1]+red[2]+red[3]));
}

__global__ void k_final(const double* __restrict__ lossacc, float* __restrict__ out){
  out[0] = (float)(*lossacc * (1.0 / ((double)NCLS * (double)NCLS)));
}

extern "C" void kernel_launch(void* const* d_in, const int* in_sizes, int n_in,
                              void* d_out, int out_size, void* d_ws, size_t ws_size,
                              hipStream_t stream) {
  const float* xr  = (const float*)d_in[0];
  const float* xi  = (const float*)d_in[1];
  const int*   tgt = (const int*)d_in[2];
  float* out = (float*)d_out;
  int n = in_sizes[2];                 // 131072 rows

  char* w = (char*)d_ws;
  int* counts   = (int*)w;                      // 1024
  int* offsets  = counts + NCLS;                // 1024
  int* cursor   = offsets + NCLS;               // 1024
  int* index    = cursor + NCLS;                // n
  float* T      = (float*)(index + n);          // 2048*256
  float* sq     = T + NTOT*DIM;                 // 2048
  float* invbw  = sq + NTOT;                    // 5 (+3 pad)
  double* lossd = (double*)(invbw + 8);         // 1
  float* Ppart  = (float*)(lossd + 1);          // 4096*256 = 4 MB
  float* Pcol   = Ppart + 4*NCLS*DIM;           // 32*256

  k_init<<<1, 1024, 0, stream>>>(counts, lossd);
  k_hist<<<256, 256, 0, stream>>>(tgt, n, counts);
  k_scan<<<1, 1024, 0, stream>>>(counts, offsets, cursor);
  k_scatter<<<256, 256, 0, stream>>>(tgt, n, cursor, index);
  k_gather<<<4*NCLS, 256, 0, stream>>>(xr, xi, index, counts, offsets, Ppart);
  k_combine<<<NTOT/4, 256, 0, stream>>>(Ppart, counts, T, sq);
  k_colsum<<<32, 256, 0, stream>>>(T, Pcol);
  k_bw<<<1, 256, 0, stream>>>(sq, Pcol, invbw);
  k_mmd<<<dim3(32, 32), 256, 0, stream>>>(T, sq, invbw, lossd);
  k_final<<<1, 1, 0, stream>>>(lossd, out);
}

// Round 10
// 144.516 us; speedup vs baseline: 1.0535x; 1.0535x over previous
//
#include <hip/hip_runtime.h>

#define NCLS 1024
#define DIM  256
#define NTOT 2048   // 2*NCLS rows in "total"

__device__ __forceinline__ float4 f4add(float4 a, float4 b){
  return make_float4(a.x+b.x, a.y+b.y, a.z+b.z, a.w+b.w);
}

// ---------------- init ---------------------------------------------------------
__global__ void k_init(int* counts){
  int t = threadIdx.x;
  if (t < NCLS) counts[t] = 0;
}

// ---------------- histogram of targets (LDS-staged) ---------------------------
__global__ __launch_bounds__(256) void k_hist(const int* __restrict__ tgt, int n,
                                              int* __restrict__ counts){
  __shared__ int h[NCLS];
  for (int i = threadIdx.x; i < NCLS; i += blockDim.x) h[i] = 0;
  __syncthreads();
  for (int i = blockIdx.x*blockDim.x + threadIdx.x; i < n; i += gridDim.x*blockDim.x)
    atomicAdd(&h[tgt[i]], 1);
  __syncthreads();
  for (int i = threadIdx.x; i < NCLS; i += blockDim.x)
    if (h[i]) atomicAdd(&counts[i], h[i]);
}

// ---------------- exclusive scan over 1024 counts (single block) --------------
__global__ void k_scan(const int* __restrict__ counts, int* __restrict__ offsets,
                       int* __restrict__ cursor){
  __shared__ int buf[NCLS];
  int t = threadIdx.x;
  int v = counts[t];
  buf[t] = v;
  __syncthreads();
  for (int o = 1; o < NCLS; o <<= 1){
    int u = (t >= o) ? buf[t-o] : 0;
    __syncthreads();
    buf[t] += u;
    __syncthreads();
  }
  int excl = buf[t] - v;
  offsets[t] = excl;
  cursor[t]  = excl;
}

// ---------------- counting-sort scatter: per-class row lists ------------------
__global__ __launch_bounds__(256) void k_scatter(const int* __restrict__ tgt, int n,
                                                 int* __restrict__ cursor,
                                                 int* __restrict__ index){
  for (int i = blockIdx.x*blockDim.x + threadIdx.x; i < n; i += gridDim.x*blockDim.x){
    int t = tgt[i];
    int pos = atomicAdd(&cursor[t], 1);
    index[pos] = i;
  }
}

// ---------------- partial gather: 4 blocks per class ---------------------------
// At the platform's random-1KB-gather ceiling (~2.5 TB/s): ~64 cache-line MSHRs
// per CU x ~375ns latency, verified by 3 structurally different load schemes
// (R6 compiler / R8 inline-asm VGPR / R9 global_load_lds) all at 105-108 us.
__global__ __launch_bounds__(256) void k_gather(const float* __restrict__ xr,
    const float* __restrict__ xi, const int* __restrict__ index,
    const int* __restrict__ counts, const int* __restrict__ offsets,
    float* __restrict__ Ppart)
{
  int bid = blockIdx.x;
  int cls = bid >> 2;
  int h   = (bid >> 1) & 1;
  int a   = bid & 1;
  int tid = threadIdx.x;
  int l = tid & 63, g = tid >> 6;
  int cnt = counts[cls], off = offsets[cls];
  int c0 = (cnt + 1) >> 1;
  int start = off + (h ? c0 : 0);
  int end   = off + (h ? cnt : c0);
  const float4* __restrict__ X4 = (const float4*)(a ? xi : xr);

  float4 s0 = make_float4(0,0,0,0), s1 = make_float4(0,0,0,0);
  int j = start + g;
  for (; j + 4 < end; j += 8){
    unsigned r0 = (unsigned)index[j];
    unsigned r1 = (unsigned)index[j+4];
    float4 v0 = X4[r0*64u + l];
    float4 v1 = X4[r1*64u + l];
    s0 = f4add(s0, v0);
    s1 = f4add(s1, v1);
  }
  if (j < end) s0 = f4add(s0, X4[(unsigned)index[j]*64u + l]);
  s0 = f4add(s0, s1);

  __shared__ float4 sh[256];
  sh[tid] = s0; __syncthreads();
  if (tid < 64){
    float4 r = f4add(f4add(sh[tid], sh[tid+64]), f4add(sh[tid+128], sh[tid+192]));
    ((float4*)Ppart)[bid*64 + tid] = r;
  }
}

// ---------------- combine partials -> T rows + sq (NO atomics) -----------------
__global__ __launch_bounds__(256) void k_combine(const float* __restrict__ Ppart,
    const int* __restrict__ counts, float* __restrict__ T, float* __restrict__ sq)
{
  int wv  = blockIdx.x*4 + (threadIdx.x >> 6);   // 0..2047 = cls*2 + a
  int cls = wv >> 1, a = wv & 1;
  int l   = threadIdx.x & 63;
  const float4* P4 = (const float4*)Ppart;
  float4 p0 = P4[(cls*4 + 0 + a)*64 + l];
  float4 p1 = P4[(cls*4 + 2 + a)*64 + l];
  float invd = 1.f / fmaxf((float)counts[cls], 1.f);
  float4 c;
  c.x = (p0.x + p1.x) * invd;
  c.y = (p0.y + p1.y) * invd;
  c.z = (p0.z + p1.z) * invd;
  c.w = (p0.w + p1.w) * invd;
  int row = a ? (NCLS + cls) : cls;
  ((float4*)T)[row*64 + l] = c;
  float v = c.x*c.x + c.y*c.y + c.z*c.z + c.w*c.w;
  #pragma unroll
  for (int o = 32; o > 0; o >>= 1) v += __shfl_down(v, o);
  if (l == 0) sq[row] = v;
}

// ---------------- column-sum partials of T (NO atomics) ------------------------
__global__ __launch_bounds__(256) void k_colsum(const float* __restrict__ T,
                                                float* __restrict__ Pcol){
  int b = blockIdx.x;
  int tid = threadIdx.x;
  int l = tid & 63, g = tid >> 6;
  const float4* T4 = (const float4*)T;
  float4 acc = make_float4(0,0,0,0);
  for (int r = b*64 + g; r < b*64 + 64; r += 4)
    acc = f4add(acc, T4[r*64 + l]);
  __shared__ float4 sh[256];
  sh[tid] = acc; __syncthreads();
  if (tid < 64){
    float4 r = f4add(f4add(sh[tid], sh[tid+64]), f4add(sh[tid+128], sh[tid+192]));
    ((float4*)Pcol)[b*64 + tid] = r;
  }
}

// ---------------- bandwidth: reduce sq + ||colsum||^2; zero lossacc ------------
// sum(dists) = 2n*sum(sq) - 2*||colsum||^2  (clamp affects only ~1e-6 diag noise)
__global__ __launch_bounds__(256) void k_bw(const float* __restrict__ sq,
    const float* __restrict__ Pcol, float* __restrict__ invbw,
    double* __restrict__ lossacc){
  int t = threadIdx.x;
  double acc = 0.0;
  for (int i = t; i < NTOT; i += 256) acc += (double)sq[i];
  float cs = 0.f;
  for (int b = 0; b < 32; ++b) cs += Pcol[b*DIM + t];
  double c2 = (double)cs * (double)cs;
  #pragma unroll
  for (int o = 32; o > 0; o >>= 1){
    acc += __shfl_down(acc, o);
    c2  += __shfl_down(c2, o);
  }
  __shared__ double ra[4], rc[4];
  int lane = t & 63, wid = t >> 6;
  if (lane == 0){ ra[wid] = acc; rc[wid] = c2; }
  __syncthreads();
  if (t == 0){
    double S_sq = ra[0]+ra[1]+ra[2]+ra[3];
    double S_cs = rc[0]+rc[1]+rc[2]+rc[3];
    double S1 = 2.0*(double)NTOT*S_sq - 2.0*S_cs;
    double bw = S1 / ((double)NTOT*(double)NTOT - (double)NTOT) / 4.0;
    #pragma unroll
    for (int k = 0; k < 5; ++k)
      invbw[k] = (float)(1.0 / (bw * (double)(1 << k)));
    *lossacc = 0.0;
  }
}

// ---------------- fused Gram + 5-exp kernel + signed reduction ----------------
// Symmetric: only bx>=by computed; off-diagonal blocks weighted x2 (exact —
// dot(i,j) is bitwise-symmetric). Transposed LDS tiles: 2 ds_read_b128 per
// 16 FMA (broadcast/2-way patterns, conflict-free).
__global__ __launch_bounds__(256) void k_mmd(const float* __restrict__ T,
    const float* __restrict__ sq, const float* __restrict__ invbw,
    double* __restrict__ lossacc)
{
  int bx = blockIdx.x, by = blockIdx.y;
  if (bx < by) return;
  __shared__ float AsT[64][68];   // [k][row]
  __shared__ float BsT[64][68];   // [k][col]
  __shared__ float red[4];
  int tid = threadIdx.x;
  int tx = tid & 15, ty = tid >> 4;
  int rowA = by*64, rowB = bx*64;
  float acc[4][4];
  #pragma unroll
  for (int a = 0; a < 4; ++a)
    #pragma unroll
    for (int b = 0; b < 4; ++b) acc[a][b] = 0.f;

  for (int kk = 0; kk < DIM; kk += 64){
    #pragma unroll
    for (int it = 0; it < 4; ++it){
      int idx = it*256 + tid;
      int r = idx >> 4, c4 = idx & 15;
      float4 va = *(const float4*)&T[(rowA + r)*DIM + kk + c4*4];
      float4 vb = *(const float4*)&T[(rowB + r)*DIM + kk + c4*4];
      AsT[c4*4+0][r] = va.x; AsT[c4*4+1][r] = va.y;
      AsT[c4*4+2][r] = va.z; AsT[c4*4+3][r] = va.w;
      BsT[c4*4+0][r] = vb.x; BsT[c4*4+1][r] = vb.y;
      BsT[c4*4+2][r] = vb.z; BsT[c4*4+3][r] = vb.w;
    }
    __syncthreads();
    #pragma unroll 8
    for (int k = 0; k < 64; ++k){
      float4 av = *(const float4*)&AsT[k][ty*4];
      float4 bv = *(const float4*)&BsT[k][tx*4];
      acc[0][0] += av.x*bv.x; acc[0][1] += av.x*bv.y; acc[0][2] += av.x*bv.z; acc[0][3] += av.x*bv.w;
      acc[1][0] += av.y*bv.x; acc[1][1] += av.y*bv.y; acc[1][2] += av.y*bv.z; acc[1][3] += av.y*bv.w;
      acc[2][0] += av.z*bv.x; acc[2][1] += av.z*bv.y; acc[2][2] += av.z*bv.z; acc[2][3] += av.z*bv.w;
      acc[3][0] += av.w*bv.x; acc[3][1] += av.w*bv.y; acc[3][2] += av.w*bv.z; acc[3][3] += av.w*bv.w;
    }
    __syncthreads();
  }

  float i0 = invbw[0], i1 = invbw[1], i2 = invbw[2], i3 = invbw[3], i4 = invbw[4];
  float wgt = (bx > by) ? 2.f : 1.f;
  float lacc = 0.f;
  #pragma unroll
  for (int a = 0; a < 4; ++a){
    int i = rowA + ty*4 + a;
    float sqi  = sq[i];
    float sgnI = (i < NCLS) ? 1.f : -1.f;
    #pragma unroll
    for (int b = 0; b < 4; ++b){
      int j = rowB + tx*4 + b;
      float d = sqi + sq[j] - 2.f*acc[a][b];
      d = fmaxf(d, 0.f);
      float w = __expf(-d*i0) + __expf(-d*i1) + __expf(-d*i2) + __expf(-d*i3) + __expf(-d*i4);
      lacc += ((j < NCLS) ? sgnI : -sgnI) * w;
    }
  }
  lacc *= wgt;
  #pragma unroll
  for (int o = 32; o > 0; o >>= 1) lacc += __shfl_down(lacc, o);
  int lane = tid & 63, wid = tid >> 6;
  if (lane == 0) red[wid] = lacc;
  __syncthreads();
  if (tid == 0) atomicAdd(lossacc, (double)(red[0]+red[1]+red[2]+red[3]));
}

__global__ void k_final(const double* __restrict__ lossacc, float* __restrict__ out){
  out[0] = (float)(*lossacc * (1.0 / ((double)NCLS * (double)NCLS)));
}

extern "C" void kernel_launch(void* const* d_in, const int* in_sizes, int n_in,
                              void* d_out, int out_size, void* d_ws, size_t ws_size,
                              hipStream_t stream) {
  const float* xr  = (const float*)d_in[0];
  const float* xi  = (const float*)d_in[1];
  const int*   tgt = (const int*)d_in[2];
  float* out = (float*)d_out;
  int n = in_sizes[2];                 // 131072 rows

  char* w = (char*)d_ws;
  int* counts   = (int*)w;                      // 1024
  int* offsets  = counts + NCLS;                // 1024
  int* cursor   = offsets + NCLS;               // 1024
  int* index    = cursor + NCLS;                // n
  float* T      = (float*)(index + n);          // 2048*256
  float* sq     = T + NTOT*DIM;                 // 2048
  float* invbw  = sq + NTOT;                    // 5 (+3 pad)
  double* lossd = (double*)(invbw + 8);         // 1
  float* Ppart  = (float*)(lossd + 1);          // 4096*256 = 4 MB
  float* Pcol   = Ppart + 4*NCLS*DIM;           // 32*256

  k_init<<<1, 1024, 0, stream>>>(counts);
  k_hist<<<256, 256, 0, stream>>>(tgt, n, counts);
  k_scan<<<1, 1024, 0, stream>>>(counts, offsets, cursor);
  k_scatter<<<256, 256, 0, stream>>>(tgt, n, cursor, index);
  k_gather<<<4*NCLS, 256, 0, stream>>>(xr, xi, index, counts, offsets, Ppart);
  k_combine<<<NTOT/4, 256, 0, stream>>>(Ppart, counts, T, sq);
  k_colsum<<<32, 256, 0, stream>>>(T, Pcol);
  k_bw<<<1, 256, 0, stream>>>(sq, Pcol, invbw, lossd);
  k_mmd<<<dim3(32, 32), 256, 0, stream>>>(T, sq, invbw, lossd);
  k_final<<<1, 1, 0, stream>>>(lossd, out);
}